// Round 4
// baseline (2605.613 us; speedup 1.0000x reference)
//
#include <hip/hip_runtime.h>
#include <stdint.h>

#define HID   128
#define OUT   4096
#define NWG   32          // persistent EP workgroups, slice = 128 cols each
#define SLICE 128         // OUT / NWG
#define NT    256
#define NXB   128         // one-shot xW1 worker blocks
#define RPX   512         // rows per xW1 block (65536 / 128)

typedef unsigned long long u64;

__device__ __forceinline__ u64 pk(uint32_t tag, float v) {
  return ((u64)tag << 32) | (u64)__float_as_uint(v);
}

// blockIdx < NWG: persistent EP workgroup. blockIdx >= NWG: one-shot xW1 worker.
__global__ __launch_bounds__(NT, 1) void k_all(
    const float* __restrict__ x,
    const float* __restrict__ W1,
    const float* __restrict__ W2,
    const float* __restrict__ b_h,
    const float* __restrict__ b_out,
    const float* __restrict__ h0,
    const float* __restrict__ o0,
    const int* __restrict__ n_iter_p,
    const float* __restrict__ eps_p,
    u64* __restrict__ pbuf,   // [2][NWG][HID] tagged h-gradient partials
    u64* __restrict__ xw1p,   // [NXB][HID] tagged xW1 partials
    float* __restrict__ out) {

  __shared__ __attribute__((aligned(16))) float red[8 * HID];  // 4 KB
  __shared__ __attribute__((aligned(16))) float rh_s[HID];
  __shared__ __attribute__((aligned(16))) float ro_s[SLICE];

  const int t = threadIdx.x;

  if (blockIdx.x >= NWG) {
    // ---------------- xW1 worker: partial of clip(x,0,1) @ W1 over 512 rows ------
    const int b = blockIdx.x - NWG;
    const int c4 = (t & 31) * 4;
    const int rseg = t >> 5;
    const int r0 = b * RPX + rseg * 64;
    float4 acc = make_float4(0.f, 0.f, 0.f, 0.f);
#pragma unroll 8
    for (int k = 0; k < 64; ++k) {
      const int r = r0 + k;
      const float rx = fminf(fmaxf(x[r], 0.f), 1.f);
      const float4 wv = *(const float4*)&W1[(size_t)r * HID + c4];
      acc.x = fmaf(rx, wv.x, acc.x); acc.y = fmaf(rx, wv.y, acc.y);
      acc.z = fmaf(rx, wv.z, acc.z); acc.w = fmaf(rx, wv.w, acc.w);
    }
    *(float4*)&red[rseg * HID + c4] = acc;
    __syncthreads();
    if (t < HID) {
      const float s = ((red[t] + red[HID + t]) + (red[2*HID + t] + red[3*HID + t]))
                    + ((red[4*HID + t] + red[5*HID + t]) + (red[6*HID + t] + red[7*HID + t]));
      __hip_atomic_store(&xw1p[b * HID + t], pk(1u, s),
                         __ATOMIC_RELAXED, __HIP_MEMORY_SCOPE_AGENT);
    }
    return;
  }

  // ---------------- persistent EP workgroup ---------------------------------------
  const int wg   = blockIdx.x;
  const int cgrp = t & 31;            // cols 4*cgrp .. 4*cgrp+3 of the slice
  const int rgrp = t >> 5;            // rows 16*rgrp .. 16*rgrp+15
  const int n_iter = *n_iter_p;
  const float eps  = *eps_p;

  // ---- W2 chunk into registers (16 rows x 4 cols = 64 VGPRs), PINNED ----
  float4 w[16];
  {
    const float* wp = W2 + (size_t)(rgrp * 16) * OUT + wg * SLICE + cgrp * 4;
#pragma unroll
    for (int r = 0; r < 16; ++r)
      w[r] = *(const float4*)(wp + (size_t)r * OUT);
  }
#pragma unroll
  for (int r = 0; r < 16; ++r)
    asm volatile("" : "+v"(w[r].x), "+v"(w[r].y), "+v"(w[r].z), "+v"(w[r].w));

  // ---- gather xW1 partials (tag-polled, fixed order -> identical in all WGs) ----
  float bhx = 0.f, hh = 0.f, mh = 0.f, vh = 0.f;
  if (t < HID) {
    float s = 0.f;
#pragma unroll 1
    for (int ch = 0; ch < 8; ++ch) {
      float vals[16]; unsigned got = 0u;
      while (got != 0xFFFFu) {
#pragma unroll
        for (int k = 0; k < 16; ++k) if (!(got & (1u << k))) {
          const u64 v = __hip_atomic_load(&xw1p[(ch * 16 + k) * HID + t],
                                          __ATOMIC_RELAXED, __HIP_MEMORY_SCOPE_AGENT);
          if ((uint32_t)(v >> 32) == 1u) { vals[k] = __uint_as_float((uint32_t)v); got |= 1u << k; }
        }
        if (got != 0xFFFFu) __builtin_amdgcn_s_sleep(1);
      }
#pragma unroll
      for (int k = 0; k < 16; ++k) s += vals[k];
    }
    bhx = b_h[t] + s;
    hh  = h0[t];
    rh_s[t] = fminf(fmaxf(hh, 0.f), 1.f);
  }
  float oo = 0.f, mo = 0.f, vo = 0.f, bo = 0.f;
  if (t < SLICE) {
    oo = o0[wg * SLICE + t];
    bo = b_out[wg * SLICE + t];
    ro_s[t] = fminf(fmaxf(oo, 0.f), 1.f);
  }
  __syncthreads();

  float bp1 = 1.f, bp2 = 1.f;

  for (int it = 0; it < n_iter; ++it) {
    bp1 *= 0.9f; bp2 *= 0.999f;
    const float c1 = 1.f / (1.f - bp1);
    const float c2 = 1.f / (1.f - bp2);
    u64* pb = pbuf + (size_t)(it & 1) * (NWG * HID);
    const uint32_t tag = (uint32_t)(it + 1);

    // ---- Pass B (registers): partial of W2 @ r_o over this thread's 4 cols ----
    float aB[16];
    {
      const float4 ro4 = *(const float4*)&ro_s[cgrp * 4];
#pragma unroll
      for (int r = 0; r < 16; ++r)
        aB[r] = fmaf(w[r].x, ro4.x, fmaf(w[r].y, ro4.y,
                 fmaf(w[r].z, ro4.z, w[r].w * ro4.w)));
    }
    // ---- fold over 32 lanes (cgrp) while scattering the 16 rows ----
    {
#pragma unroll
      for (int r = 0; r < 8; ++r) {  // xor 16: 16 -> 8 rows
        const float keep = (cgrp & 16) ? aB[r + 8] : aB[r];
        const float send = (cgrp & 16) ? aB[r]     : aB[r + 8];
        aB[r] = keep + __shfl_xor(send, 16, 64);
      }
#pragma unroll
      for (int r = 0; r < 4; ++r) {  // xor 8: 8 -> 4
        const float keep = (cgrp & 8) ? aB[r + 4] : aB[r];
        const float send = (cgrp & 8) ? aB[r]     : aB[r + 4];
        aB[r] = keep + __shfl_xor(send, 8, 64);
      }
#pragma unroll
      for (int r = 0; r < 2; ++r) {  // xor 4: 4 -> 2
        const float keep = (cgrp & 4) ? aB[r + 2] : aB[r];
        const float send = (cgrp & 4) ? aB[r]     : aB[r + 2];
        aB[r] = keep + __shfl_xor(send, 4, 64);
      }
      {                              // xor 2: 2 -> 1
        const float keep = (cgrp & 2) ? aB[1] : aB[0];
        const float send = (cgrp & 2) ? aB[0] : aB[1];
        aB[0] = keep + __shfl_xor(send, 2, 64);
      }
      aB[0] += __shfl_xor(aB[0], 1, 64);  // duplicate pair -> full 32-lane sum
    }
    // ---- publish tagged partial AS EARLY AS POSSIBLE (per-wave, no fence) ----
    if (!(cgrp & 1)) {
      const int prow = rgrp * 16 + ((cgrp >> 1) & 1) + 2 * ((cgrp >> 2) & 1)
                     + 4 * ((cgrp >> 3) & 1) + 8 * ((cgrp >> 4) & 1);
      __hip_atomic_store(&pb[wg * HID + prow], pk(tag, aB[0]),
                         __ATOMIC_RELAXED, __HIP_MEMORY_SCOPE_AGENT);
    }

    // ---- Pass A (registers, overlaps propagation): r_h @ W2 partial ----
    {
      float4 aA = make_float4(0.f, 0.f, 0.f, 0.f);
      const float4* rhp = (const float4*)&rh_s[rgrp * 16];
      const float4 rh0 = rhp[0], rh1 = rhp[1], rh2 = rhp[2], rh3 = rhp[3];
      const float rhv[16] = {rh0.x, rh0.y, rh0.z, rh0.w, rh1.x, rh1.y, rh1.z, rh1.w,
                             rh2.x, rh2.y, rh2.z, rh2.w, rh3.x, rh3.y, rh3.z, rh3.w};
#pragma unroll
      for (int r = 0; r < 16; ++r) {
        aA.x = fmaf(w[r].x, rhv[r], aA.x); aA.y = fmaf(w[r].y, rhv[r], aA.y);
        aA.z = fmaf(w[r].z, rhv[r], aA.z); aA.w = fmaf(w[r].w, rhv[r], aA.w);
      }
      *(float4*)&red[rgrp * SLICE + cgrp * 4] = aA;
    }
    __syncthreads();

    // ---- g_o + Adam(o) (one column per thread t<128) ----
    if (t < SLICE) {
      const float s = ((red[t] + red[SLICE + t]) + (red[2*SLICE + t] + red[3*SLICE + t]))
                    + ((red[4*SLICE + t] + red[5*SLICE + t]) + (red[6*SLICE + t] + red[7*SLICE + t]));
      const float ro_old = fminf(fmaxf(oo, 0.f), 1.f);
      const float g = (oo >= 0.f && oo <= 1.f) ? (ro_old - bo - s) : 0.f;
      mo = 0.9f * mo + 0.1f * g;
      vo = 0.999f * vo + 0.001f * g * g;
      oo -= eps * (mo * c1) / (sqrtf(vo * c2) + 1e-8f);
      ro_s[t] = fminf(fmaxf(oo, 0.f), 1.f);   // next reader: Pass B after end-of-loop sync
    }

    // ---- poll all 32 WGs' tagged partials, fixed-order sum, Adam(h) ----
    if (t < HID) {
      float gv[32]; uint32_t got = 0u;
      while (got != 0xFFFFFFFFu) {
#pragma unroll
        for (int wi = 0; wi < 32; ++wi) if (!(got & (1u << wi))) {
          const u64 v = __hip_atomic_load(&pb[wi * HID + t],
                                          __ATOMIC_RELAXED, __HIP_MEMORY_SCOPE_AGENT);
          if ((uint32_t)(v >> 32) == tag) { gv[wi] = __uint_as_float((uint32_t)v); got |= 1u << wi; }
        }
      }
      float s4[8];
#pragma unroll
      for (int k = 0; k < 8; ++k)
        s4[k] = (gv[4*k] + gv[4*k+1]) + (gv[4*k+2] + gv[4*k+3]);
      const float gsum = ((s4[0] + s4[1]) + (s4[2] + s4[3])) + ((s4[4] + s4[5]) + (s4[6] + s4[7]));
      const float rh_old = fminf(fmaxf(hh, 0.f), 1.f);
      const float g = (hh >= 0.f && hh <= 1.f) ? (rh_old - bhx - gsum) : 0.f;
      mh = 0.9f * mh + 0.1f * g;
      vh = 0.999f * vh + 0.001f * g * g;
      hh -= eps * (mh * c1) / (sqrtf(vh * c2) + 1e-8f);
      rh_s[t] = fminf(fmaxf(hh, 0.f), 1.f);
    }
    __syncthreads();
  }

  if (t < SLICE) out[wg * SLICE + t] = oo;
}

// ---------------- launcher ----------------------------------------------------------
extern "C" void kernel_launch(void* const* d_in, const int* in_sizes, int n_in,
                              void* d_out, int out_size, void* d_ws, size_t ws_size,
                              hipStream_t stream) {
  const float* x     = (const float*)d_in[0];
  const float* W1    = (const float*)d_in[1];
  const float* W2    = (const float*)d_in[2];
  // d_in[3] = b_in (unused by the reference)
  const float* b_h   = (const float*)d_in[4];
  const float* b_out = (const float*)d_in[5];
  const float* h0    = (const float*)d_in[6];
  const float* o0    = (const float*)d_in[7];
  const int*   nit   = (const int*)d_in[8];
  const float* eps   = (const float*)d_in[9];

  u64*   pbuf = (u64*)d_ws;                         // [2][32][128] u64 = 64 KB
  u64*   xw1p = (u64*)((char*)d_ws + 65536);        // [128][128] u64 = 128 KB
  float* out  = (float*)d_out;

  // no memset needed: poisoned 0xAAAAAAAA tags never match (xw1 tag=1, iter tags=1..n)
  k_all<<<dim3(NWG + NXB), dim3(NT), 0, stream>>>(x, W1, W2, b_h, b_out, h0, o0,
                                                  nit, eps, pbuf, xw1p, out);
}

// Round 5
// 1081.092 us; speedup vs baseline: 2.4102x; 2.4102x over previous
//
#include <hip/hip_runtime.h>
#include <stdint.h>

#define HID   128
#define OUT   4096
#define NWG   8           // persistent EP workgroups, slice = 512 cols each
#define SLICE 512         // OUT / NWG
#define NT    512
#define NXB   128         // one-shot xW1 worker blocks
#define RPX   512         // rows per xW1 block (65536 / 128)

typedef unsigned long long u64;

__device__ __forceinline__ u64 pk(uint32_t tag, float v) {
  return ((u64)tag << 32) | (u64)__float_as_uint(v);
}

// blockIdx < NWG: persistent EP workgroup. blockIdx >= NWG: one-shot xW1 worker.
__global__ __launch_bounds__(NT, 1) void k_all(
    const float* __restrict__ x,
    const float* __restrict__ W1,
    const float* __restrict__ W2,
    const float* __restrict__ b_h,
    const float* __restrict__ b_out,
    const float* __restrict__ h0,
    const float* __restrict__ o0,
    const int* __restrict__ n_iter_p,
    const float* __restrict__ eps_p,
    u64* __restrict__ pbuf,   // [2][NWG][HID] tagged h-gradient partials
    u64* __restrict__ xw1p,   // [NXB][HID] tagged xW1 partials
    float* __restrict__ out) {

  __shared__ __attribute__((aligned(16))) float red[8 * SLICE];  // 16 KB
  __shared__ __attribute__((aligned(16))) float rh_s[HID];
  __shared__ __attribute__((aligned(16))) float ro_s[SLICE];

  const int t = threadIdx.x;

  if (blockIdx.x >= NWG) {
    // ---------------- xW1 worker: partial of clip(x,0,1) @ W1 over 512 rows ------
    const int b = blockIdx.x - NWG;
    const int c4 = (t & 31) * 4;
    const int rseg = t >> 5;            // 0..15
    const int r0 = b * RPX + rseg * 32;
    float4 acc = make_float4(0.f, 0.f, 0.f, 0.f);
#pragma unroll 8
    for (int k = 0; k < 32; ++k) {
      const int r = r0 + k;
      const float rx = fminf(fmaxf(x[r], 0.f), 1.f);
      const float4 wv = *(const float4*)&W1[(size_t)r * HID + c4];
      acc.x = fmaf(rx, wv.x, acc.x); acc.y = fmaf(rx, wv.y, acc.y);
      acc.z = fmaf(rx, wv.z, acc.z); acc.w = fmaf(rx, wv.w, acc.w);
    }
    *(float4*)&red[rseg * HID + c4] = acc;
    __syncthreads();
    if (t < HID) {
      float s = 0.f;
#pragma unroll
      for (int k = 0; k < 16; k += 4)
        s += (red[k*HID + t] + red[(k+1)*HID + t]) + (red[(k+2)*HID + t] + red[(k+3)*HID + t]);
      __hip_atomic_store(&xw1p[b * HID + t], pk(1u, s),
                         __ATOMIC_RELAXED, __HIP_MEMORY_SCOPE_AGENT);
    }
    return;
  }

  // ---------------- persistent EP workgroup ---------------------------------------
  const int wg = blockIdx.x;
  const int cg = t & 63;               // lane id; owns cols cg + 64*k (k=0..7)
  const int rg = t >> 6;               // wave id; owns rows rg*16 .. rg*16+15
  const int n_iter = *n_iter_p;
  const float eps  = *eps_p;

  // ---- W2 chunk into registers: w2[r][k] = W2[rg*16+r][wg*512 + cg + 64k] ----
  // (lane-consecutive cols per (r,k) -> coalesced dword loads; PINNED vs remat)
  float w2[16][8];
  {
    const float* wp = W2 + (size_t)(rg * 16) * OUT + wg * SLICE + cg;
#pragma unroll
    for (int r = 0; r < 16; ++r)
#pragma unroll
      for (int k = 0; k < 8; ++k)
        w2[r][k] = wp[(size_t)r * OUT + 64 * k];
  }
#pragma unroll
  for (int r = 0; r < 16; ++r)
    asm volatile("" : "+v"(w2[r][0]), "+v"(w2[r][1]), "+v"(w2[r][2]), "+v"(w2[r][3]),
                      "+v"(w2[r][4]), "+v"(w2[r][5]), "+v"(w2[r][6]), "+v"(w2[r][7]));

  // ---- gather xW1 partials (tag-polled, fixed order -> identical in all WGs) ----
  float bhx = 0.f, hh = 0.f, mh = 0.f, vh = 0.f;
  if (t < HID) {
    float s = 0.f;
#pragma unroll 1
    for (int ch = 0; ch < 8; ++ch) {
      float vals[16]; unsigned got = 0u;
      while (got != 0xFFFFu) {
#pragma unroll
        for (int k = 0; k < 16; ++k) if (!(got & (1u << k))) {
          const u64 v = __hip_atomic_load(&xw1p[(ch * 16 + k) * HID + t],
                                          __ATOMIC_RELAXED, __HIP_MEMORY_SCOPE_AGENT);
          if ((uint32_t)(v >> 32) == 1u) { vals[k] = __uint_as_float((uint32_t)v); got |= 1u << k; }
        }
        if (got != 0xFFFFu) __builtin_amdgcn_s_sleep(1);
      }
#pragma unroll
      for (int k = 0; k < 16; ++k) s += vals[k];
    }
    bhx = b_h[t] + s;
    hh  = h0[t];
    rh_s[t] = fminf(fmaxf(hh, 0.f), 1.f);
  }
  float oo = o0[wg * SLICE + t];       // one o-column per thread (SLICE == NT)
  float mo = 0.f, vo = 0.f;
  const float bo = b_out[wg * SLICE + t];
  ro_s[t] = fminf(fmaxf(oo, 0.f), 1.f);
  __syncthreads();

  float bp1 = 1.f, bp2 = 1.f;

  for (int it = 0; it < n_iter; ++it) {
    bp1 *= 0.9f; bp2 *= 0.999f;
    const float c1 = 1.f / (1.f - bp1);
    const float c2 = 1.f / (1.f - bp2);
    u64* pb = pbuf + (size_t)(it & 1) * (NWG * HID);
    const uint32_t tag = (uint32_t)(it + 1);

    // ---- Pass B (registers): rows rg*16..+15, partial over this thread's 8 cols ----
    float aB[16];
    {
      float rov[8];
#pragma unroll
      for (int k = 0; k < 8; ++k) rov[k] = ro_s[cg + 64 * k];   // stride-1/lane, conflict-free
#pragma unroll
      for (int r = 0; r < 16; ++r) {
        float a = w2[r][0] * rov[0];
#pragma unroll
        for (int k = 1; k < 8; ++k) a = fmaf(w2[r][k], rov[k], a);
        aB[r] = a;
      }
    }
    // ---- in-wave fold: 64 lanes x 16 rows -> each lane quad holds one row sum ----
    {
#pragma unroll
      for (int r = 0; r < 8; ++r) {   // xor 32: 16 -> 8 rows (+8*b5)
        const float keep = (cg & 32) ? aB[r + 8] : aB[r];
        const float send = (cg & 32) ? aB[r]     : aB[r + 8];
        aB[r] = keep + __shfl_xor(send, 32, 64);
      }
#pragma unroll
      for (int r = 0; r < 4; ++r) {   // xor 16: 8 -> 4 (+4*b4)
        const float keep = (cg & 16) ? aB[r + 4] : aB[r];
        const float send = (cg & 16) ? aB[r]     : aB[r + 4];
        aB[r] = keep + __shfl_xor(send, 16, 64);
      }
#pragma unroll
      for (int r = 0; r < 2; ++r) {   // xor 8: 4 -> 2 (+2*b3)
        const float keep = (cg & 8) ? aB[r + 2] : aB[r];
        const float send = (cg & 8) ? aB[r]     : aB[r + 2];
        aB[r] = keep + __shfl_xor(send, 8, 64);
      }
      {                               // xor 4: 2 -> 1 (+1*b2)
        const float keep = (cg & 4) ? aB[1] : aB[0];
        const float send = (cg & 4) ? aB[0] : aB[1];
        aB[0] = keep + __shfl_xor(send, 4, 64);
      }
      aB[0] += __shfl_xor(aB[0], 2, 64);   // duplicate folds
      aB[0] += __shfl_xor(aB[0], 1, 64);
    }
    // ---- publish tagged partial EARLY (row = rg*16 + cg/4, lanes cg%4==0) ----
    if ((cg & 3) == 0) {
      __hip_atomic_store(&pb[wg * HID + rg * 16 + (cg >> 2)], pk(tag, aB[0]),
                         __ATOMIC_RELAXED, __HIP_MEMORY_SCOPE_AGENT);
    }

    // ---- Pass A (registers, overlaps propagation): r_h @ W2 over this thread's rows ----
    {
      float aA[8] = {0.f, 0.f, 0.f, 0.f, 0.f, 0.f, 0.f, 0.f};
#pragma unroll
      for (int r = 0; r < 16; ++r) {
        const float rh = rh_s[rg * 16 + r];          // wave-uniform broadcast
#pragma unroll
        for (int k = 0; k < 8; ++k) aA[k] = fmaf(w2[r][k], rh, aA[k]);
      }
#pragma unroll
      for (int k = 0; k < 8; ++k)
        red[rg * SLICE + cg + 64 * k] = aA[k];       // stride-1/lane, conflict-free
    }
    __syncthreads();

    // ---- g_o + Adam(o): one column (= t) per thread ----
    {
      const float s = ((red[t] + red[SLICE + t]) + (red[2*SLICE + t] + red[3*SLICE + t]))
                    + ((red[4*SLICE + t] + red[5*SLICE + t]) + (red[6*SLICE + t] + red[7*SLICE + t]));
      const float ro_old = fminf(fmaxf(oo, 0.f), 1.f);
      const float g = (oo >= 0.f && oo <= 1.f) ? (ro_old - bo - s) : 0.f;
      mo = 0.9f * mo + 0.1f * g;
      vo = 0.999f * vo + 0.001f * g * g;
      oo -= eps * (mo * c1) / (sqrtf(vo * c2) + 1e-8f);
      ro_s[t] = fminf(fmaxf(oo, 0.f), 1.f);          // read next iter after end barrier
    }

    // ---- poll 8 WGs' tagged partials, fixed-order sum, Adam(h) (replicated) ----
    if (t < HID) {
      float gv[8]; uint32_t got = 0u;
      while (got != 0xFFu) {
#pragma unroll
        for (int wi = 0; wi < 8; ++wi) if (!(got & (1u << wi))) {
          const u64 v = __hip_atomic_load(&pb[wi * HID + t],
                                          __ATOMIC_RELAXED, __HIP_MEMORY_SCOPE_AGENT);
          if ((uint32_t)(v >> 32) == tag) { gv[wi] = __uint_as_float((uint32_t)v); got |= 1u << wi; }
        }
      }
      const float gsum = ((gv[0] + gv[1]) + (gv[2] + gv[3]))
                       + ((gv[4] + gv[5]) + (gv[6] + gv[7]));
      const float rh_old = fminf(fmaxf(hh, 0.f), 1.f);
      const float g = (hh >= 0.f && hh <= 1.f) ? (rh_old - bhx - gsum) : 0.f;
      mh = 0.9f * mh + 0.1f * g;
      vh = 0.999f * vh + 0.001f * g * g;
      hh -= eps * (mh * c1) / (sqrtf(vh * c2) + 1e-8f);
      rh_s[t] = fminf(fmaxf(hh, 0.f), 1.f);
    }
    __syncthreads();
  }

  out[wg * SLICE + t] = oo;
}

// ---------------- launcher ----------------------------------------------------------
extern "C" void kernel_launch(void* const* d_in, const int* in_sizes, int n_in,
                              void* d_out, int out_size, void* d_ws, size_t ws_size,
                              hipStream_t stream) {
  const float* x     = (const float*)d_in[0];
  const float* W1    = (const float*)d_in[1];
  const float* W2    = (const float*)d_in[2];
  // d_in[3] = b_in (unused by the reference)
  const float* b_h   = (const float*)d_in[4];
  const float* b_out = (const float*)d_in[5];
  const float* h0    = (const float*)d_in[6];
  const float* o0    = (const float*)d_in[7];
  const int*   nit   = (const int*)d_in[8];
  const float* eps   = (const float*)d_in[9];

  u64*   pbuf = (u64*)d_ws;                         // [2][8][128] u64 = 16 KB
  u64*   xw1p = (u64*)((char*)d_ws + 16384);        // [128][128] u64 = 128 KB
  float* out  = (float*)d_out;

  // no memset needed: poisoned 0xAAAAAAAA tags never match (xw1 tag=1, iter tags=1..n)
  k_all<<<dim3(NWG + NXB), dim3(NT), 0, stream>>>(x, W1, W2, b_h, b_out, h0, o0,
                                                  nit, eps, pbuf, xw1p, out);
}

// Round 6
// 603.347 us; speedup vs baseline: 4.3186x; 1.7918x over previous
//
#include <hip/hip_runtime.h>
#include <stdint.h>

#define HID   128
#define OUT   4096
#define NWG   8           // persistent EP workgroups, slice = 512 cols each
#define SLICE 512         // OUT / NWG
#define NT    512
#define NXB   128         // one-shot xW1 worker blocks
#define RPX   512         // rows per xW1 block (65536 / 128)

typedef unsigned long long u64;

__device__ __forceinline__ u64 pk(uint32_t tag, float v) {
  return ((u64)tag << 32) | (u64)__float_as_uint(v);
}

// blockIdx < NWG: persistent EP workgroup. blockIdx >= NWG: one-shot xW1 worker.
__global__ __launch_bounds__(NT, 1) void k_all(
    const float* __restrict__ x,
    const float* __restrict__ W1,
    const float* __restrict__ W2,
    const float* __restrict__ b_h,
    const float* __restrict__ b_out,
    const float* __restrict__ h0,
    const float* __restrict__ o0,
    const int* __restrict__ n_iter_p,
    const float* __restrict__ eps_p,
    u64* __restrict__ pbuf,   // [2][NWG][HID] tagged h-gradient partials
    u64* __restrict__ xw1p,   // [NXB][HID] tagged xW1 partials
    float* __restrict__ out) {

  __shared__ __attribute__((aligned(16))) float red[8 * SLICE];  // 16 KB
  __shared__ __attribute__((aligned(16))) float rh_s[HID];
  __shared__ __attribute__((aligned(16))) float ro_s[SLICE];

  const int t = threadIdx.x;

  if (blockIdx.x >= NWG) {
    // ---------------- xW1 worker: partial of clip(x,0,1) @ W1 over 512 rows ------
    const int b = blockIdx.x - NWG;
    const int c4 = (t & 31) * 4;
    const int rseg = t >> 5;            // 0..15
    const int r0 = b * RPX + rseg * 32;
    float4 acc = make_float4(0.f, 0.f, 0.f, 0.f);
#pragma unroll 8
    for (int k = 0; k < 32; ++k) {
      const int r = r0 + k;
      const float rx = fminf(fmaxf(x[r], 0.f), 1.f);
      const float4 wv = *(const float4*)&W1[(size_t)r * HID + c4];
      acc.x = fmaf(rx, wv.x, acc.x); acc.y = fmaf(rx, wv.y, acc.y);
      acc.z = fmaf(rx, wv.z, acc.z); acc.w = fmaf(rx, wv.w, acc.w);
    }
    *(float4*)&red[rseg * HID + c4] = acc;
    __syncthreads();
    if (t < HID) {
      float s = 0.f;
#pragma unroll
      for (int k = 0; k < 16; k += 4)
        s += (red[k*HID + t] + red[(k+1)*HID + t]) + (red[(k+2)*HID + t] + red[(k+3)*HID + t]);
      __hip_atomic_store(&xw1p[b * HID + t], pk(1u, s),
                         __ATOMIC_RELAXED, __HIP_MEMORY_SCOPE_AGENT);
    }
    return;
  }

  // ---------------- persistent EP workgroup ---------------------------------------
  const int wg = blockIdx.x;
  const int cg = t & 63;               // lane id; owns cols cg + 64*k (k=0..7)
  const int rg = t >> 6;               // wave id; owns rows rg*16 .. rg*16+15
  const int n_iter = *n_iter_p;
  const float eps  = *eps_p;

  // ---- W2 chunk into registers: w2[r][k] = W2[rg*16+r][wg*512 + cg + 64k] ----
  float w2[16][8];
  {
    const float* wp = W2 + (size_t)(rg * 16) * OUT + wg * SLICE + cg;
#pragma unroll
    for (int r = 0; r < 16; ++r)
#pragma unroll
      for (int k = 0; k < 8; ++k)
        w2[r][k] = wp[(size_t)r * OUT + 64 * k];
  }
#pragma unroll
  for (int r = 0; r < 16; ++r)
    asm volatile("" : "+v"(w2[r][0]), "+v"(w2[r][1]), "+v"(w2[r][2]), "+v"(w2[r][3]),
                      "+v"(w2[r][4]), "+v"(w2[r][5]), "+v"(w2[r][6]), "+v"(w2[r][7]));

  // ---- gather xW1 partials: BATCHED unconditional tagged loads, fixed-order sum ----
  float bhx = 0.f, hh = 0.f, mh = 0.f, vh = 0.f;
  if (t < HID) {
    float s = 0.f;
#pragma unroll 1
    for (int ch = 0; ch < 8; ++ch) {
      u64 v[16];
      for (;;) {
#pragma unroll
        for (int k = 0; k < 16; ++k)
          v[k] = __hip_atomic_load(&xw1p[(ch * 16 + k) * HID + t],
                                   __ATOMIC_RELAXED, __HIP_MEMORY_SCOPE_AGENT);
        uint32_t bad = 0u;
#pragma unroll
        for (int k = 0; k < 16; ++k) bad |= ((uint32_t)(v[k] >> 32)) ^ 1u;
        if (bad == 0u) break;
        __builtin_amdgcn_s_sleep(2);
      }
#pragma unroll
      for (int k = 0; k < 16; ++k) s += __uint_as_float((uint32_t)v[k]);
    }
    bhx = b_h[t] + s;
    hh  = h0[t];
    rh_s[t] = fminf(fmaxf(hh, 0.f), 1.f);
  }
  float oo = o0[wg * SLICE + t];       // one o-column per thread (SLICE == NT)
  float mo = 0.f, vo = 0.f;
  const float bo = b_out[wg * SLICE + t];
  ro_s[t] = fminf(fmaxf(oo, 0.f), 1.f);
  __syncthreads();

  float bp1 = 1.f, bp2 = 1.f;

  for (int it = 0; it < n_iter; ++it) {
    bp1 *= 0.9f; bp2 *= 0.999f;
    const float c1 = 1.f / (1.f - bp1);
    const float c2 = 1.f / (1.f - bp2);
    u64* pb = pbuf + (size_t)(it & 1) * (NWG * HID);
    const uint32_t tag = (uint32_t)(it + 1);

    // ---- Pass B (registers): rows rg*16..+15, partial over this thread's 8 cols ----
    float aB[16];
    {
      float rov[8];
#pragma unroll
      for (int k = 0; k < 8; ++k) rov[k] = ro_s[cg + 64 * k];   // stride-1/lane, conflict-free
#pragma unroll
      for (int r = 0; r < 16; ++r) {
        float a = w2[r][0] * rov[0];
#pragma unroll
        for (int k = 1; k < 8; ++k) a = fmaf(w2[r][k], rov[k], a);
        aB[r] = a;
      }
    }
    // ---- in-wave fold: 64 lanes x 16 rows -> one row sum per lane quad ----
    {
#pragma unroll
      for (int r = 0; r < 8; ++r) {   // xor 32: 16 -> 8 rows
        const float keep = (cg & 32) ? aB[r + 8] : aB[r];
        const float send = (cg & 32) ? aB[r]     : aB[r + 8];
        aB[r] = keep + __shfl_xor(send, 32, 64);
      }
#pragma unroll
      for (int r = 0; r < 4; ++r) {   // xor 16: 8 -> 4
        const float keep = (cg & 16) ? aB[r + 4] : aB[r];
        const float send = (cg & 16) ? aB[r]     : aB[r + 4];
        aB[r] = keep + __shfl_xor(send, 16, 64);
      }
#pragma unroll
      for (int r = 0; r < 2; ++r) {   // xor 8: 4 -> 2
        const float keep = (cg & 8) ? aB[r + 2] : aB[r];
        const float send = (cg & 8) ? aB[r]     : aB[r + 2];
        aB[r] = keep + __shfl_xor(send, 8, 64);
      }
      {                               // xor 4: 2 -> 1
        const float keep = (cg & 4) ? aB[1] : aB[0];
        const float send = (cg & 4) ? aB[0] : aB[1];
        aB[0] = keep + __shfl_xor(send, 4, 64);
      }
      aB[0] += __shfl_xor(aB[0], 2, 64);   // duplicate folds
      aB[0] += __shfl_xor(aB[0], 1, 64);
    }
    // ---- publish tagged partial EARLY (row = rg*16 + cg/4, lanes cg%4==0) ----
    if ((cg & 3) == 0) {
      __hip_atomic_store(&pb[wg * HID + rg * 16 + (cg >> 2)], pk(tag, aB[0]),
                         __ATOMIC_RELAXED, __HIP_MEMORY_SCOPE_AGENT);
    }

    // ---- Pass A (registers, overlaps propagation): r_h @ W2 over this thread's rows ----
    {
      float aA[8] = {0.f, 0.f, 0.f, 0.f, 0.f, 0.f, 0.f, 0.f};
#pragma unroll
      for (int r = 0; r < 16; ++r) {
        const float rh = rh_s[rg * 16 + r];          // wave-uniform broadcast
#pragma unroll
        for (int k = 0; k < 8; ++k) aA[k] = fmaf(w2[r][k], rh, aA[k]);
      }
#pragma unroll
      for (int k = 0; k < 8; ++k)
        red[rg * SLICE + cg + 64 * k] = aA[k];       // stride-1/lane, conflict-free
    }
    __syncthreads();

    // ---- g_o + Adam(o): one column (= t) per thread ----
    {
      const float s = ((red[t] + red[SLICE + t]) + (red[2*SLICE + t] + red[3*SLICE + t]))
                    + ((red[4*SLICE + t] + red[5*SLICE + t]) + (red[6*SLICE + t] + red[7*SLICE + t]));
      const float ro_old = fminf(fmaxf(oo, 0.f), 1.f);
      const float g = (oo >= 0.f && oo <= 1.f) ? (ro_old - bo - s) : 0.f;
      mo = 0.9f * mo + 0.1f * g;
      vo = 0.999f * vo + 0.001f * g * g;
      oo -= eps * (mo * c1) / (sqrtf(vo * c2) + 1e-8f);
      ro_s[t] = fminf(fmaxf(oo, 0.f), 1.f);          // read next iter after end barrier
    }

    // ---- poll all 8 WGs: BATCHED unconditional loads, one vmcnt per round ----
    if (t < HID) {
      float gv[8];
      for (;;) {
        u64 v[8];
#pragma unroll
        for (int wi = 0; wi < 8; ++wi)
          v[wi] = __hip_atomic_load(&pb[wi * HID + t],
                                    __ATOMIC_RELAXED, __HIP_MEMORY_SCOPE_AGENT);
        uint32_t bad = 0u;
#pragma unroll
        for (int wi = 0; wi < 8; ++wi) bad |= ((uint32_t)(v[wi] >> 32)) ^ tag;
        if (bad == 0u) {
#pragma unroll
          for (int wi = 0; wi < 8; ++wi) gv[wi] = __uint_as_float((uint32_t)v[wi]);
          break;
        }
        __builtin_amdgcn_s_sleep(1);
      }
      const float gsum = ((gv[0] + gv[1]) + (gv[2] + gv[3]))
                       + ((gv[4] + gv[5]) + (gv[6] + gv[7]));
      const float rh_old = fminf(fmaxf(hh, 0.f), 1.f);
      const float g = (hh >= 0.f && hh <= 1.f) ? (rh_old - bhx - gsum) : 0.f;
      mh = 0.9f * mh + 0.1f * g;
      vh = 0.999f * vh + 0.001f * g * g;
      hh -= eps * (mh * c1) / (sqrtf(vh * c2) + 1e-8f);
      rh_s[t] = fminf(fmaxf(hh, 0.f), 1.f);
    }
    __syncthreads();
  }

  out[wg * SLICE + t] = oo;
}

// ---------------- launcher ----------------------------------------------------------
extern "C" void kernel_launch(void* const* d_in, const int* in_sizes, int n_in,
                              void* d_out, int out_size, void* d_ws, size_t ws_size,
                              hipStream_t stream) {
  const float* x     = (const float*)d_in[0];
  const float* W1    = (const float*)d_in[1];
  const float* W2    = (const float*)d_in[2];
  // d_in[3] = b_in (unused by the reference)
  const float* b_h   = (const float*)d_in[4];
  const float* b_out = (const float*)d_in[5];
  const float* h0    = (const float*)d_in[6];
  const float* o0    = (const float*)d_in[7];
  const int*   nit   = (const int*)d_in[8];
  const float* eps   = (const float*)d_in[9];

  u64*   pbuf = (u64*)d_ws;                         // [2][8][128] u64 = 16 KB
  u64*   xw1p = (u64*)((char*)d_ws + 16384);        // [128][128] u64 = 128 KB
  float* out  = (float*)d_out;

  // no memset needed: poisoned 0xAAAAAAAA tags never match (xw1 tag=1, iter tags=1..n)
  k_all<<<dim3(NWG + NXB), dim3(NT), 0, stream>>>(x, W1, W2, b_h, b_out, h0, o0,
                                                  nit, eps, pbuf, xw1p, out);
}